// Round 2
// baseline (175.977 us; speedup 1.0000x reference)
//
#include <hip/hip_runtime.h>
#include <hip/hip_bf16.h>
#include <stdint.h>

// Problem constants
#define BATCH 8
#define CH    256     // C
#define CQK   32      // query/key channels
#define NPIX  4096    // H*W
#define MALL  320     // CQK + CQK + CH combined projection rows

using bfrag = __attribute__((ext_vector_type(8))) short;     // 8 bf16 = 4 VGPR (MFMA A/B)
using f32x4 = __attribute__((ext_vector_type(4))) float;     // MFMA C/D
using u32x2 = __attribute__((ext_vector_type(2))) unsigned int;

#define MFMA16(A, B, C) __builtin_amdgcn_mfma_f32_16x16x32_bf16(A, B, C, 0, 0, 0)

#if __has_builtin(__builtin_amdgcn_exp2f)
#define EXP2(x) __builtin_amdgcn_exp2f(x)
#else
#define EXP2(x) exp2f(x)
#endif

__device__ __forceinline__ unsigned short f2bf(float f) {
  union { float f; unsigned int u; } v; v.f = f;
  unsigned int r = v.u + 0x7FFFu + ((v.u >> 16) & 1u);   // RNE
  return (unsigned short)(r >> 16);
}

__device__ __forceinline__ void gload_lds16(const void* g, void* l) {
  __builtin_amdgcn_global_load_lds(
      (const __attribute__((address_space(1))) unsigned int*)g,
      (__attribute__((address_space(3))) unsigned int*)l, 16, 0, 0);
}

// ---------------- kernel 0: cast weights to bf16 ----------------
__global__ void prep_kernel(const float* __restrict__ Wf, const float* __restrict__ Wg,
                            const float* __restrict__ Wh, const float* __restrict__ Wv,
                            unsigned short* __restrict__ Wall, unsigned short* __restrict__ Wvb) {
  int i = blockIdx.x * 256 + threadIdx.x;
  if (i < MALL * CH) {
    int m = i >> 8, c = i & 255;
    float v = (m < CQK)     ? Wf[m * CH + c]
            : (m < 2 * CQK) ? Wg[(m - CQK) * CH + c]
                            : Wh[(m - 2 * CQK) * CH + c];
    Wall[i] = f2bf(v);
  }
  if (i < CH * CH) Wvb[i] = f2bf(Wv[i]);
}

// ---------------- kernel 1: f,g,h projections (MFMA GEMM) ----------------
// out[m][n] = sum_c Wall[m][c] * x[b][c][n]  for one 64-pixel tile; M=320, K=256.
// Q is pre-scaled by log2(e) so the attention softmax can use raw exp2.
__global__ __launch_bounds__(256, 2)
void proj_kernel(const float* __restrict__ x, const unsigned short* __restrict__ Wall,
                 const float* __restrict__ bfb, const float* __restrict__ bgb,
                 const float* __restrict__ bhb,
                 unsigned short* __restrict__ Qo, unsigned short* __restrict__ Ko,
                 unsigned short* __restrict__ Vo) {
  __shared__ char xT[64 * 512];  // xT[n][c] bf16, rows 512B, 16B-chunk XOR (n&7)
  const int b  = blockIdx.x & 7;
  const int n0 = (blockIdx.x >> 3) * 64;
  const int tid = threadIdx.x;
  const int lane = tid & 63, wave = tid >> 6;
  const int lr = lane & 15, g = lane >> 4;

  // load + transpose x tile (fp32 -> bf16)
  for (int it = 0; it < 16; ++it) {
    int c = it * 16 + wave * 4 + g;
    int nn = lr * 4;
    const float4 v = *(const float4*)(x + (size_t)(b * CH + c) * NPIX + n0 + nn);
    const float* vp = (const float*)&v;
#pragma unroll
    for (int j = 0; j < 4; ++j) {
      int n = nn + j;
      int byteoff = n * 512 + (((c >> 3) ^ (n & 7)) << 4) + ((c & 7) * 2);
      *(unsigned short*)(xT + byteoff) = f2bf(vp[j]);
    }
  }
  __syncthreads();

  f32x4 acc[5][4] = {};
  for (int ks = 0; ks < 8; ++ks) {
    bfrag bfr[4];
#pragma unroll
    for (int nt = 0; nt < 4; ++nt) {
      int n = nt * 16 + lr;
      bfr[nt] = *(const bfrag*)(xT + n * 512 + (((ks * 4 + g) ^ (n & 7)) << 4));
    }
#pragma unroll
    for (int i = 0; i < 5; ++i) {
      int m = (wave + 4 * i) * 16 + lr;
      bfrag afr = *(const bfrag*)(Wall + (size_t)m * CH + ks * 32 + g * 8);
#pragma unroll
      for (int nt = 0; nt < 4; ++nt) acc[i][nt] = MFMA16(afr, bfr[nt], acc[i][nt]);
    }
  }

  const float L2E = 1.4426950408889634f;
#pragma unroll
  for (int i = 0; i < 5; ++i) {
    const int mt = wave + 4 * i;
#pragma unroll
    for (int nt = 0; nt < 4; ++nt) {
      const int n = n0 + nt * 16 + lr;
      if (mt < 2) {                     // f -> Q (scaled by log2 e)
        float v0 = (acc[i][nt][0] + bfb[mt * 16 + 4 * g + 0]) * L2E;
        float v1 = (acc[i][nt][1] + bfb[mt * 16 + 4 * g + 1]) * L2E;
        float v2 = (acc[i][nt][2] + bfb[mt * 16 + 4 * g + 2]) * L2E;
        float v3 = (acc[i][nt][3] + bfb[mt * 16 + 4 * g + 3]) * L2E;
        u32x2 pk;
        pk[0] = (unsigned)f2bf(v0) | ((unsigned)f2bf(v1) << 16);
        pk[1] = (unsigned)f2bf(v2) | ((unsigned)f2bf(v3) << 16);
        *(u32x2*)(Qo + (size_t)(b * NPIX + n) * CQK + mt * 16 + 4 * g) = pk;
      } else if (mt < 4) {              // g -> K
        int k0 = (mt - 2) * 16 + 4 * g;
        float v0 = acc[i][nt][0] + bgb[k0 + 0];
        float v1 = acc[i][nt][1] + bgb[k0 + 1];
        float v2 = acc[i][nt][2] + bgb[k0 + 2];
        float v3 = acc[i][nt][3] + bgb[k0 + 3];
        u32x2 pk;
        pk[0] = (unsigned)f2bf(v0) | ((unsigned)f2bf(v1) << 16);
        pk[1] = (unsigned)f2bf(v2) | ((unsigned)f2bf(v3) << 16);
        *(u32x2*)(Ko + (size_t)(b * NPIX + n) * CQK + k0) = pk;
      } else {                          // h -> V [c][n]
#pragma unroll
        for (int r = 0; r < 4; ++r) {
          int c = mt * 16 + 4 * g + r - 64;
          Vo[(size_t)(b * CH + c) * NPIX + n] = f2bf(acc[i][nt][r] + bhb[c]);
        }
      }
    }
  }
}

// ---------------- kernel 2: flash attention (register K/V, LDS only for P) ---
// Per block: one batch, 64-query tile, 4 waves, KV tiles of 64.
// K/V fragments load straight from global (L2-resident, batch pinned to XCD).
// P[64q][64j] goes through one 8KB LDS buffer for cross-wave re-fragmentation.
// Raw s_barrier + lgkmcnt(0) only — vmcnt is never force-drained (T4).
__global__ __launch_bounds__(256)
void attn_kernel(const unsigned short* __restrict__ Qg, const unsigned short* __restrict__ Kg,
                 const unsigned short* __restrict__ Vg, unsigned short* __restrict__ Og) {
  __shared__ char Pb[8192];                 // P[64 q][64 j] bf16, 16B-chunk XOR (q&7)

  const int b  = blockIdx.x & 7;            // batch == XCD pin
  const int q0 = (blockIdx.x >> 3) * 64;
  const int tid = threadIdx.x;
  const int lane = tid & 63, wave = tid >> 6;
  const int lr = lane & 15, g = lane >> 4;

  const unsigned short* Qbase = Qg + (size_t)(b * NPIX + q0) * CQK;
  const unsigned short* Kfp   = Kg + (size_t)b * NPIX * CQK + (size_t)(16 * wave + lr) * CQK + g * 8;
  const unsigned short* Vfp   = Vg + (size_t)b * CH * NPIX + g * 8;

  // persistent Q fragments (B-operand of S^T)
  bfrag qf[4];
#pragma unroll
  for (int nt = 0; nt < 4; ++nt)
    qf[nt] = *(const bfrag*)(Qbase + (nt * 16 + lr) * CQK + g * 8);

  f32x4 acc[4][4] = {};
  float lp[4] = {0.f, 0.f, 0.f, 0.f};
  const int pwG = 2 * wave + (g >> 1);      // P write chunk index

  bfrag kf = *(const bfrag*)(Kfp);          // K fragment, tile 0

  for (int t = 0; t < 64; ++t) {
    // ---- issue V fragment loads for tile t (latency hidden by S phase)
    bfrag vf[2][4];
#pragma unroll
    for (int ks = 0; ks < 2; ++ks)
#pragma unroll
      for (int nt = 0; nt < 4; ++nt)
        vf[ks][nt] = *(const bfrag*)(Vfp + (size_t)(64 * wave + nt * 16 + lr) * NPIX
                                         + t * 64 + ks * 32);

    // ---- S^T phase: wave's 16-j block x 64 q, exp2, pack, P write
#pragma unroll
    for (int nt = 0; nt < 4; ++nt) {
      f32x4 zero = {0.f, 0.f, 0.f, 0.f};
      f32x4 st = MFMA16(kf, qf[nt], zero);
      float p0 = EXP2(st[0]), p1 = EXP2(st[1]);
      float p2 = EXP2(st[2]), p3 = EXP2(st[3]);
      lp[nt] += (p0 + p1) + (p2 + p3);
      union { float f; unsigned u; } u0, u1, u2, u3;
      u0.f = p0; u1.f = p1; u2.f = p2; u3.f = p3;
      u32x2 pk;
      pk[0] = ((u0.u + 0x8000u) >> 16) | ((u1.u + 0x8000u) & 0xFFFF0000u);
      pk[1] = ((u2.u + 0x8000u) >> 16) | ((u3.u + 0x8000u) & 0xFFFF0000u);
      int q = nt * 16 + lr;
      *(u32x2*)(Pb + q * 128 + ((pwG ^ (q & 7)) << 4) + ((g & 1) << 3)) = pk;
    }

    // next tile's K fragment (covered until next iteration's S phase)
    kf = *(const bfrag*)(Kfp + (size_t)(((t + 1) & 63) * 64) * CQK);

    asm volatile("s_waitcnt lgkmcnt(0)" ::: "memory");   // own P writes done
    __builtin_amdgcn_s_barrier();                        // all P writes visible

    // ---- PV phase: wave owns c-block [64*wave, 64*wave+64)
#pragma unroll
    for (int ks = 0; ks < 2; ++ks) {
      bfrag pf[4];
#pragma unroll
      for (int mt = 0; mt < 4; ++mt) {
        int q = mt * 16 + lr;
        pf[mt] = *(const bfrag*)(Pb + q * 128 + (((ks * 4 + g) ^ (q & 7)) << 4));
      }
#pragma unroll
      for (int mt = 0; mt < 4; ++mt)
#pragma unroll
        for (int nt = 0; nt < 4; ++nt)
          acc[mt][nt] = MFMA16(pf[mt], vf[ks][nt], acc[mt][nt]);
    }

    asm volatile("s_waitcnt lgkmcnt(0)" ::: "memory");   // own P reads done
    __builtin_amdgcn_s_barrier();                        // safe to overwrite P
  }

  // ---- epilogue: softmax denominators and normalized store
#pragma unroll
  for (int nt = 0; nt < 4; ++nt) {
    lp[nt] += __shfl_xor(lp[nt], 16);
    lp[nt] += __shfl_xor(lp[nt], 32);
  }
  float* lred = (float*)Pb;   // reuse P region
  if (lane < 16) {
#pragma unroll
    for (int nt = 0; nt < 4; ++nt) lred[wave * 64 + nt * 16 + lr] = lp[nt];
  }
  __syncthreads();
  float inv[4][4];
#pragma unroll
  for (int mt = 0; mt < 4; ++mt)
#pragma unroll
    for (int r = 0; r < 4; ++r) {
      int q = mt * 16 + 4 * g + r;
      float s = lred[q] + lred[64 + q] + lred[128 + q] + lred[192 + q];
      inv[mt][r] = 1.0f / s;
    }
#pragma unroll
  for (int mt = 0; mt < 4; ++mt)
#pragma unroll
    for (int nt = 0; nt < 4; ++nt) {
      int c = 64 * wave + nt * 16 + lr;
#pragma unroll
      for (int r = 0; r < 4; ++r) {
        int q = q0 + mt * 16 + 4 * g + r;
        Og[(size_t)(b * NPIX + q) * CH + c] = f2bf(acc[mt][nt][r] * inv[mt][r]);
      }
    }
}

// ---------------- kernel 3: v-projection + residual ----------------
// out[b][m][n] = x[b][m][n] + gamma * (sum_c Wv[m][c]*attH[b][n][c] + bv[m])
__global__ __launch_bounds__(256, 2)
void vproj_kernel(const unsigned short* __restrict__ attn, const unsigned short* __restrict__ Wvb,
                  const float* __restrict__ bv, const float* __restrict__ x,
                  const float* __restrict__ gamma, float* __restrict__ out) {
  __shared__ char at[64 * 512];   // attH tile [64 n][256 c] bf16, swizzled
  const int b  = blockIdx.x & 7;
  const int n0 = (blockIdx.x >> 3) * 64;
  const int tid = threadIdx.x;
  const int lane = tid & 63, wave = tid >> 6;
  const int lr = lane & 15, g = lane >> 4;

#pragma unroll
  for (int i = 0; i < 8; ++i) {
    int ch = i * 256 + tid;
    int n = ch >> 5, G = ch & 31;
    gload_lds16(attn + (size_t)(b * NPIX + n0 + n) * CH + (G ^ (n & 7)) * 8,
                at + (i * 256 + wave * 64) * 16);
  }
  __syncthreads();

  f32x4 acc[4][4] = {};
  for (int ks = 0; ks < 8; ++ks) {
    bfrag bfr[4];
#pragma unroll
    for (int nt = 0; nt < 4; ++nt) {
      int n = nt * 16 + lr;
      bfr[nt] = *(const bfrag*)(at + n * 512 + (((ks * 4 + g) ^ (n & 7)) << 4));
    }
#pragma unroll
    for (int i = 0; i < 4; ++i) {
      int m = (wave * 4 + i) * 16 + lr;
      bfrag afr = *(const bfrag*)(Wvb + (size_t)m * CH + ks * 32 + g * 8);
#pragma unroll
      for (int nt = 0; nt < 4; ++nt) acc[i][nt] = MFMA16(afr, bfr[nt], acc[i][nt]);
    }
  }
  const float gam = gamma[0];
#pragma unroll
  for (int i = 0; i < 4; ++i)
#pragma unroll
    for (int nt = 0; nt < 4; ++nt) {
      int n = n0 + nt * 16 + lr;
#pragma unroll
      for (int r = 0; r < 4; ++r) {
        int m = (wave * 4 + i) * 16 + 4 * g + r;
        size_t off = (size_t)(b * CH + m) * NPIX + n;
        out[off] = x[off] + gam * (acc[i][nt][r] + bv[m]);
      }
    }
}

extern "C" void kernel_launch(void* const* d_in, const int* in_sizes, int n_in,
                              void* d_out, int out_size, void* d_ws, size_t ws_size,
                              hipStream_t stream) {
  const float* x   = (const float*)d_in[0];
  const float* Wf  = (const float*)d_in[1];
  const float* bfb = (const float*)d_in[2];
  const float* Wg  = (const float*)d_in[3];
  const float* bgb = (const float*)d_in[4];
  const float* Wh  = (const float*)d_in[5];
  const float* bhb = (const float*)d_in[6];
  const float* Wv  = (const float*)d_in[7];
  const float* bv  = (const float*)d_in[8];
  const float* gam = (const float*)d_in[9];
  float* out = (float*)d_out;

  char* ws = (char*)d_ws;
  unsigned short* Wall = (unsigned short*)(ws);              // 163840 B
  unsigned short* Wvb  = (unsigned short*)(ws + 163840);     // 131072 B
  unsigned short* Q    = (unsigned short*)(ws + 294912);     // 2 MB
  unsigned short* K    = (unsigned short*)(ws + 2392064);    // 2 MB
  unsigned short* V    = (unsigned short*)(ws + 4489216);    // 16 MB
  unsigned short* attn = (unsigned short*)(ws + 21266432);   // 16 MB (end ~38 MB)

  prep_kernel<<<320, 256, 0, stream>>>(Wf, Wg, Wh, Wv, Wall, Wvb);
  proj_kernel<<<512, 256, 0, stream>>>(x, Wall, bfb, bgb, bhb, Q, K, V);
  attn_kernel<<<512, 256, 0, stream>>>(Q, K, V, attn);
  vproj_kernel<<<512, 256, 0, stream>>>(attn, Wvb, bv, x, gam, out);
}